// Round 6
// baseline (1009.014 us; speedup 1.0000x reference)
//
#include <hip/hip_runtime.h>

// DEPTree gfx950 — Round 6: mega-kernel, fully hierarchical barriers.
// R4/R5 post-mortem: ~20us/barrier came from single-cacheline atomic/poll
// contention at the device coherence point (432 contenders), not fences.
// Now: arrive 16->27->8 hierarchy, broadcast global->XCD->group, leader-only
// XCD fences, 7 barriers (levels 2..0 + final run serially in block 0).

#define DD 128
#define NN 21845
#define NPOS 18
#define NDEP 46
#define NCH 21844
#define NB2 202            // pos(18) + levels 3..6 (4*46)
#define GRID 432
#define NGRP 27
#define NBAR 7
#define NHB 171

typedef __attribute__((ext_vector_type(8))) short short8;
typedef __attribute__((ext_vector_type(4))) float f32x4;
#define AGENT __HIP_MEMORY_SCOPE_AGENT

// meta int offsets (all counters padded to 64B lines)
#define M_CLAIM  0                       // [NBAR][8][16]
#define M_GARR   (NBAR * 8 * 16)         // [NBAR][27][16]
#define M_GLOB   (M_GARR + NBAR * NGRP * 16)   // [NBAR][16]
#define M_READY  (M_GLOB + NBAR * 16)
#define M_GGO    (M_READY + NBAR * 16)
#define M_XGO    (M_GGO + NBAR * 16)     // [NBAR][8][16]
#define M_GRGO   (M_XGO + NBAR * 8 * 16) // [NBAR][27][16]
#define M_NXCD   (M_GRGO + NBAR * NGRP * 16)
#define META_INTS (M_NXCD + 16)

__device__ __forceinline__ unsigned short f2bf(float f) {
    union { float f; unsigned int u; } v; v.f = f;
    unsigned int r = v.u + 0x7fffu + ((v.u >> 16) & 1u);   // RNE
    return (unsigned short)(r >> 16);
}
__device__ __forceinline__ float bf2f(unsigned short s) {
    union { unsigned int u; float f; } v; v.u = ((unsigned int)s) << 16;
    return v.f;
}

// decode flat child index j -> level l, local child c, bucket b (NB2 space,
// only levels 3..6; b=-1 otherwise)
__device__ __forceinline__ void decode_child(int j, const int* __restrict__ dep_ids,
                                             int& l, int& c, int& b) {
    int base = 0, sz = 4;
    l = 0;
    while (j >= base + sz) { base += sz; sz <<= 2; ++l; }
    c = j - base;
    if (l >= 3) {
        int did = dep_ids[base + 1 + c];
        b = NPOS + (l - 3) * NDEP + did;
    } else {
        b = -1;
    }
}

__device__ __forceinline__ void gridbar(int* meta, int idx) {
    __syncthreads();
    if (threadIdx.x == 0) {
        asm volatile("s_waitcnt vmcnt(0) lgkmcnt(0)" ::: "memory");
        int xcd;
        asm volatile("s_getreg_b32 %0, hwreg(HW_REG_XCC_ID)" : "=s"(xcd));
        xcd &= 7;
        int g = blockIdx.x >> 4;
        bool xlead = (__hip_atomic_fetch_add(&meta[M_CLAIM + (idx * 8 + xcd) * 16],
                                             1, __ATOMIC_RELAXED, AGENT) == 0);
        if (idx == 0 && xlead)
            __hip_atomic_fetch_add(&meta[M_NXCD], 1, __ATOMIC_ACQ_REL, AGENT);
        int ga = __hip_atomic_fetch_add(&meta[M_GARR + (idx * NGRP + g) * 16],
                                        1, __ATOMIC_ACQ_REL, AGENT);
        bool glead = (ga == 15);
        if (glead)
            __hip_atomic_fetch_add(&meta[M_GLOB + idx * 16], 1, __ATOMIC_ACQ_REL, AGENT);
        if (xlead) {
            while (__hip_atomic_load(&meta[M_GLOB + idx * 16], __ATOMIC_ACQUIRE, AGENT) < NGRP)
                __builtin_amdgcn_s_sleep(4);
            int nx = __hip_atomic_load(&meta[M_NXCD], __ATOMIC_ACQUIRE, AGENT);
            __threadfence();                 // wb+inv this XCD's L2 (leader only)
            asm volatile("s_waitcnt vmcnt(0)" ::: "memory");
            int r = __hip_atomic_fetch_add(&meta[M_READY + idx * 16], 1,
                                           __ATOMIC_ACQ_REL, AGENT) + 1;
            if (r == nx) {
                __hip_atomic_store(&meta[M_GGO + idx * 16], 1, __ATOMIC_RELEASE, AGENT);
            } else {
                while (__hip_atomic_load(&meta[M_GGO + idx * 16], __ATOMIC_ACQUIRE, AGENT) == 0)
                    __builtin_amdgcn_s_sleep(4);
            }
            __hip_atomic_store(&meta[M_XGO + (idx * 8 + xcd) * 16], 1,
                               __ATOMIC_RELEASE, AGENT);
        }
        if (glead) {
            while (__hip_atomic_load(&meta[M_XGO + (idx * 8 + xcd) * 16],
                                     __ATOMIC_ACQUIRE, AGENT) == 0)
                __builtin_amdgcn_s_sleep(4);
            __hip_atomic_store(&meta[M_GRGO + (idx * NGRP + g) * 16], 1,
                               __ATOMIC_RELEASE, AGENT);
        }
        while (__hip_atomic_load(&meta[M_GRGO + (idx * NGRP + g) * 16],
                                 __ATOMIC_ACQUIRE, AGENT) == 0)
            __builtin_amdgcn_s_sleep(8);
    }
    __syncthreads();
}

// one 64-row x 128-col MFMA tile; 4 waves x (16 rows, 8 n-tiles), K=128
template <int MODE>
__device__ __forceinline__ void gemm_tile(
        int2 e, const int* __restrict__ perm, const unsigned short* __restrict__ Wt,
        const float* __restrict__ bias, const float* __restrict__ embf,
        const unsigned short* __restrict__ xb, const unsigned short* __restrict__ uprev,
        unsigned short* __restrict__ outr) {
    int bucket = e.x & 255;
    int rows = e.x >> 8;
    int rowstart = e.y;
    int lane = threadIdx.x & 63;
    int w = threadIdx.x >> 6;
    int lr = lane & 15;
    int kk = (lane >> 4) * 8;
    const short8 zero8 = {0, 0, 0, 0, 0, 0, 0, 0};

    int m_a = w * 16 + lr;
    bool valid_a = m_a < rows;
    int rid_a = valid_a ? perm[rowstart + m_a] : 0;

    short8 afr[4];
    if (MODE == 0) {
        const float* ar = embf + (size_t)rid_a * DD + kk;
#pragma unroll
        for (int s = 0; s < 4; ++s) {
            float4 lo = *(const float4*)(ar + s * 32);
            float4 hi = *(const float4*)(ar + s * 32 + 4);
            short8 a;
            a[0] = (short)f2bf(lo.x); a[1] = (short)f2bf(lo.y);
            a[2] = (short)f2bf(lo.z); a[3] = (short)f2bf(lo.w);
            a[4] = (short)f2bf(hi.x); a[5] = (short)f2bf(hi.y);
            a[6] = (short)f2bf(hi.z); a[7] = (short)f2bf(hi.w);
            afr[s] = valid_a ? a : zero8;
        }
    } else if (MODE == 1) {
        const unsigned short* ar = xb + (size_t)rid_a * DD + kk;
#pragma unroll
        for (int s = 0; s < 4; ++s)
            afr[s] = valid_a ? *(const short8*)(ar + s * 32) : zero8;
    } else {
        const unsigned short* xr = xb + (size_t)rid_a * DD + kk;
        const unsigned short* ur = uprev + (size_t)(4 * rid_a) * DD + kk;
#pragma unroll
        for (int s = 0; s < 4; ++s) {
            short8 a = *(const short8*)(xr + s * 32);
#pragma unroll
            for (int j = 0; j < 4; ++j) {
                short8 u = *(const short8*)(ur + j * DD + s * 32);
#pragma unroll
                for (int q = 0; q < 8; ++q)
                    if ((unsigned short)u[q] > (unsigned short)a[q]) a[q] = u[q];
            }
            afr[s] = valid_a ? a : zero8;
        }
    }

    f32x4 acc[8];
#pragma unroll
    for (int t = 0; t < 8; ++t) acc[t] = (f32x4){0.f, 0.f, 0.f, 0.f};

    const unsigned short* Wb = Wt + (size_t)bucket * DD * DD;
#pragma unroll
    for (int s = 0; s < 4; ++s) {
        short8 bfr[8];
#pragma unroll
        for (int t = 0; t < 8; ++t)
            bfr[t] = *(const short8*)(Wb + (size_t)(t * 16 + lr) * DD + s * 32 + kk);
#pragma unroll
        for (int t = 0; t < 8; ++t)
            acc[t] = __builtin_amdgcn_mfma_f32_16x16x32_bf16(afr[s], bfr[t], acc[t], 0, 0, 0);
    }

    int rq[4]; bool vq[4];
#pragma unroll
    for (int q = 0; q < 4; ++q) {
        int m = w * 16 + (lane >> 4) * 4 + q;
        vq[q] = m < rows;
        rq[q] = vq[q] ? perm[rowstart + m] : 0;
    }
    const float* bb = bias + bucket * DD;
#pragma unroll
    for (int t = 0; t < 8; ++t) {
        int col = t * 16 + lr;
        float bv = bb[col];
#pragma unroll
        for (int q = 0; q < 4; ++q) {
            if (vq[q]) {
                float v = fmaxf(acc[t][q] + bv, 0.f);
                outr[(size_t)rq[q] * DD + col] = f2bf(v);
            }
        }
    }
}

__global__ __launch_bounds__(256, 2) void mega_kernel(
        const float* __restrict__ emb, const int* __restrict__ pos_ids,
        const int* __restrict__ dep_ids, const float* __restrict__ posW,
        const float* __restrict__ pos_b, const float* __restrict__ depW,
        const float* __restrict__ dep_b, float* __restrict__ out,
        int* __restrict__ meta, int* __restrict__ blk_cnt,
        int* __restrict__ ntiles, int* __restrict__ perm_pos,
        int* __restrict__ perm_dep, int2* __restrict__ tbl1,
        int2* __restrict__ tblL, unsigned short* __restrict__ Wt,
        unsigned short* __restrict__ xbf, unsigned short* __restrict__ uarena) {
    __shared__ __align__(16) char smem[9728];
    int bid = blockIdx.x;
    int tid = threadIdx.x;

    // ---- P0: convert W (blocks 0..255) + per-block hist (blocks 256..426) ----
    if (bid < 256) {
        unsigned short (*lds)[72] = (unsigned short (*)[72])smem;
        int mat = bid >> 2;
        int tile = bid & 3;
        int tk = (tile >> 1) * 64, tn = (tile & 1) * 64;
        const float* W = (mat < NPOS) ? (posW + (size_t)mat * DD * DD)
                                      : (depW + (size_t)(mat - NPOS) * DD * DD);
        unsigned short* O = Wt + (size_t)mat * DD * DD;
        int tx = tid & 63, ty = tid >> 6;
#pragma unroll
        for (int i = 0; i < 16; ++i) {
            int r = ty + i * 4;
            lds[tx][r] = f2bf(W[(size_t)(tk + r) * DD + tn + tx]);
        }
        __syncthreads();
#pragma unroll
        for (int i = 0; i < 16; ++i) {
            int r = ty + i * 4;
            O[(size_t)(tn + r) * DD + tk + tx] = lds[r][tx];
        }
    } else if (bid < 256 + NHB) {
        int* h = (int*)smem;
        for (int i = tid; i < NB2; i += 256) h[i] = 0;
        __syncthreads();
        int hb = bid - 256;
        int g = hb * 256 + tid;
        if (g < NN) {
            atomicAdd(&h[pos_ids[g]], 1);
        } else if (g < NN + NCH) {
            int l, c, b;
            decode_child(g - NN, dep_ids, l, c, b);
            if (b >= 0) atomicAdd(&h[b], 1);
        }
        __syncthreads();
        for (int i = tid; i < NB2; i += 256)
            blk_cnt[hb * NB2 + i] = h[i];
    }
    gridbar(meta, 0);

    // ---- P1: scatter + plan (blocks 0..170) ----
    if (bid < NHB) {
        int* tot = (int*)smem;             // [NB2]
        int* pre = tot + NB2;
        int* scb = pre + NB2;
        int* h   = scb + NB2;
        for (int i = tid; i < NB2; i += 256) {
            int sa = 0, sb = 0;
            for (int bb = 0; bb < NHB; ++bb) {
                int v = blk_cnt[bb * NB2 + i];
                sa += v;
                if (bb < bid) sb += v;
            }
            tot[i] = sa; pre[i] = sb; h[i] = 0;
        }
        __syncthreads();
        int wv = tid >> 6, lane = tid & 63;
        const int baseTab2[4] = {84, 340, 1364, 5460};  // perm_dep bases l=3..6
        for (int grp = wv; grp < 5; grp += 4) {
            int width = (grp == 0) ? NPOS : NDEP;
            int coff  = (grp == 0) ? 0 : NPOS + (grp - 1) * NDEP;
            int base  = (grp == 0) ? 0 : baseTab2[grp - 1];
            int c = (lane < width) ? tot[coff + lane] : 0;
            int t = (c + 63) >> 6;
            int pi = c, qi = t;
#pragma unroll
            for (int off = 1; off < 64; off <<= 1) {
                int a = __shfl_up(pi, off);
                int b2 = __shfl_up(qi, off);
                if (lane >= off) { pi += a; qi += b2; }
            }
            if (lane < width) {
                int rowstart = base + pi - c;
                scb[coff + lane] = rowstart;
                if (bid == 0) {
                    int2* tb = (grp == 0) ? tbl1 : (tblL + (grp - 1) * 302);
                    int qe = qi - t;
                    for (int k = 0; k < t; ++k) {
                        int2 ent;
                        ent.x = lane | (min(64, c - (k << 6)) << 8);
                        ent.y = rowstart + (k << 6);
                        tb[qe + k] = ent;
                    }
                    if (lane == width - 1) ntiles[grp] = qi;
                }
            }
        }
        __syncthreads();
        int g = bid * 256 + tid;
        int b = -1, payload = 0;
        if (g < NN) {
            b = pos_ids[g]; payload = g;
        } else if (g < NN + NCH) {
            int l, c;
            decode_child(g - NN, dep_ids, l, c, b);
            payload = c;
        }
        if (b >= 0) {
            int local = atomicAdd(&h[b], 1);
            int idx = scb[b] + pre[b] + local;
            if (b < NPOS) perm_pos[idx] = payload;
            else perm_dep[idx] = payload;
        }
    }
    gridbar(meta, 1);

    // u arena row offsets: U6:0 U5:16384 U4:20480 U3:21504 U2:21760 U1:21824 U0:21840
    // ---- P2: stage1 ----
    if (bid < ntiles[0])
        gemm_tile<0>(tbl1[bid], perm_pos, Wt, pos_b, emb, nullptr, nullptr, xbf);
    gridbar(meta, 2);

    const unsigned short* Wtd = Wt + (size_t)NPOS * DD * DD;
    // ---- P3: level 6 (grp 4) ----
    if (bid < ntiles[4])
        gemm_tile<1>(tblL[3 * 302 + bid], perm_dep, Wtd, dep_b, nullptr,
                     xbf + (size_t)5461 * DD, nullptr, uarena);
    gridbar(meta, 3);

    // ---- P4: level 5 (grp 3) ----
    if (bid < ntiles[3])
        gemm_tile<2>(tblL[2 * 302 + bid], perm_dep, Wtd, dep_b, nullptr,
                     xbf + (size_t)1365 * DD, uarena,
                     uarena + (size_t)16384 * DD);
    gridbar(meta, 4);

    // ---- P5: level 4 (grp 2) ----
    if (bid < ntiles[2])
        gemm_tile<2>(tblL[1 * 302 + bid], perm_dep, Wtd, dep_b, nullptr,
                     xbf + (size_t)341 * DD, uarena + (size_t)16384 * DD,
                     uarena + (size_t)20480 * DD);
    gridbar(meta, 5);

    // ---- P6: level 3 (grp 1) ----
    if (bid < ntiles[1])
        gemm_tile<2>(tblL[0 * 302 + bid], perm_dep, Wtd, dep_b, nullptr,
                     xbf + (size_t)85 * DD, uarena + (size_t)20480 * DD,
                     uarena + (size_t)21504 * DD);
    gridbar(meta, 6);

    // ---- P7: levels 2..0 + final, block 0 only (fp32 wave-GEMV) ----
    if (bid == 0) {
        float (*zbuf)[DD] = (float (*)[DD])smem;
        const int lsch[3]  = {21, 5, 1};
        const int nch[3]   = {64, 16, 4};
        const int upo[3]   = {21504, 21760, 21824};
        const int uco[3]   = {21760, 21824, 21840};
        int wv = tid >> 6, lane = tid & 63;
        int e0 = lane * 2;
        for (int t3 = 0; t3 < 3; ++t3) {
            const unsigned short* up = uarena + (size_t)upo[t3] * DD;
            unsigned short* uc = uarena + (size_t)uco[t3] * DD;
            for (int c = wv; c < nch[t3]; c += 4) {
                const unsigned short* xr = xbf + (size_t)(lsch[t3] + c) * DD;
                const unsigned short* ur = up + (size_t)(4 * c) * DD;
                unsigned short m0 = xr[e0], m1 = xr[e0 + 1];
#pragma unroll
                for (int j = 0; j < 4; ++j) {
                    unsigned short u0 = ur[j * DD + e0], u1 = ur[j * DD + e0 + 1];
                    if (u0 > m0) m0 = u0;
                    if (u1 > m1) m1 = u1;
                }
                zbuf[wv][e0] = bf2f(m0);
                zbuf[wv][e0 + 1] = bf2f(m1);
                int did = dep_ids[lsch[t3] + c];
                const float* W = depW + (size_t)did * DD * DD;
                float a0 = dep_b[did * DD + e0], a1 = dep_b[did * DD + e0 + 1];
#pragma unroll 8
                for (int k = 0; k < DD; ++k) {
                    float zk = zbuf[wv][k];
                    float2 w2 = *(const float2*)(W + (size_t)k * DD + e0);
                    a0 = fmaf(zk, w2.x, a0);
                    a1 = fmaf(zk, w2.y, a1);
                }
                uc[(size_t)c * DD + e0] = f2bf(fmaxf(a0, 0.f));
                uc[(size_t)c * DD + e0 + 1] = f2bf(fmaxf(a1, 0.f));
            }
            __syncthreads();
        }
        if (tid < DD) {
            unsigned short m = xbf[tid];
#pragma unroll
            for (int j = 0; j < 4; ++j) {
                unsigned short u = uarena[(size_t)(21840 + j) * DD + tid];
                if (u > m) m = u;
            }
            out[tid] = bf2f(m);
        }
    }
}

extern "C" void kernel_launch(void* const* d_in, const int* in_sizes, int n_in,
                              void* d_out, int out_size, void* d_ws, size_t ws_size,
                              hipStream_t stream) {
    const float* emb     = (const float*)d_in[0];
    const int*   pos_ids = (const int*)d_in[1];
    const int*   dep_ids = (const int*)d_in[2];
    const float* pos_W   = (const float*)d_in[3];
    const float* pos_b   = (const float*)d_in[4];
    const float* dep_W   = (const float*)d_in[5];
    const float* dep_b   = (const float*)d_in[6];
    float* out = (float*)d_out;

    char* p = (char*)d_ws;
    auto alloc = [&](size_t bytes) {
        char* r = p; p += (bytes + 255) & ~(size_t)255; return r;
    };
    int* meta = (int*)alloc((size_t)META_INTS * 4);
    int* blk_cnt  = (int*)alloc((size_t)NHB * NB2 * 4);
    int* ntiles   = (int*)alloc(8 * 4);
    int* perm_pos = (int*)alloc((size_t)NN * 4);
    int* perm_dep = (int*)alloc((size_t)NCH * 4);
    int2* tbl1    = (int2*)alloc(384 * 8);
    int2* tblL    = (int2*)alloc(4 * 302 * 8);
    unsigned short* Wt     = (unsigned short*)alloc((size_t)64 * DD * DD * 2);
    unsigned short* xbf    = (unsigned short*)alloc((size_t)NN * DD * 2);
    unsigned short* uarena = (unsigned short*)alloc((size_t)NCH * DD * 2);

    hipMemsetAsync(meta, 0, (size_t)META_INTS * 4, stream);
    mega_kernel<<<GRID, 256, 0, stream>>>(emb, pos_ids, dep_ids, pos_W, pos_b,
                                          dep_W, dep_b, out, meta, blk_cnt,
                                          ntiles, perm_pos, perm_dep,
                                          tbl1, tblL, Wt, xbf, uarena);
}

// Round 7
// 209.688 us; speedup vs baseline: 4.8120x; 4.8120x over previous
//
#include <hip/hip_runtime.h>

// DEPTree gfx950 — Round 7: back to multi-dispatch (grid barriers cost >=20us/hop
// on this chip, all R4-R6 variants lost). 8 dispatches, zero global atomics:
// D1 = convert W (256 blocks) || single-block LDS-only planner.
// D2..D7 = bucketed MFMA GEMMs (stage1, L6..L2). D8 = L1+L0+final GEMVs.

#define DD 128
#define NN 21845
#define NPOS 18
#define NDEP 46
#define NB 248            // 18 pos + 5*46 dep buckets (levels 2..6)
#define NCHALL 21844
#define CH_LO 20          // first bucketed child flat index (level-2 children)
#define NITEMS (NN + NCHALL - CH_LO)   // 43669

typedef __attribute__((ext_vector_type(8))) short short8;
typedef __attribute__((ext_vector_type(4))) float f32x4;

__device__ __forceinline__ unsigned short f2bf(float f) {
    union { float f; unsigned int u; } v; v.f = f;
    unsigned int r = v.u + 0x7fffu + ((v.u >> 16) & 1u);   // RNE
    return (unsigned short)(r >> 16);
}
__device__ __forceinline__ float bf2f(unsigned short s) {
    union { unsigned int u; float f; } v; v.u = ((unsigned int)s) << 16;
    return v.f;
}

// ---- D1: blocks 1..256 convert W to bf16 transposed [mat][n][k]; block 0 plans.
__global__ __launch_bounds__(1024) void prep_kernel(
        const float* __restrict__ posW, const float* __restrict__ depW,
        unsigned short* __restrict__ Wt,
        const int* __restrict__ pos_ids, const int* __restrict__ dep_ids,
        int* __restrict__ perm_pos, int* __restrict__ perm_dep,
        int* __restrict__ ntiles, int2* __restrict__ tbl1,
        int2* __restrict__ tblL) {
    __shared__ __align__(16) char smem[9216];
    int bid = blockIdx.x, tid = threadIdx.x;
    if (bid >= 1) {
        unsigned short (*lds)[72] = (unsigned short (*)[72])smem;
        int mb = bid - 1;
        int mat = mb >> 2, tile = mb & 3;
        int tk = (tile >> 1) * 64, tn = (tile & 1) * 64;
        const float* W = (mat < NPOS) ? (posW + (size_t)mat * DD * DD)
                                      : (depW + (size_t)(mat - NPOS) * DD * DD);
        unsigned short* O = Wt + (size_t)mat * DD * DD;
        int tx = tid & 63, ty = tid >> 6;            // ty 0..15
#pragma unroll
        for (int i = 0; i < 4; ++i) {
            int r = i * 16 + ty;
            lds[tx][r] = f2bf(W[(size_t)(tk + r) * DD + tn + tx]);
        }
        __syncthreads();
#pragma unroll
        for (int i = 0; i < 4; ++i) {
            int r = i * 16 + ty;
            O[(size_t)(tn + r) * DD + tk + tx] = lds[r][tx];
        }
        return;
    }
    // ---- planner: LDS-only atomics ----
    int* cnt  = (int*)smem;        // [NB]
    int* scb  = cnt + NB;          // row start per bucket
    int* tpre = scb + NB;          // tile index start per bucket (within group)
    int* rank = tpre + NB;
    for (int i = tid; i < NB; i += 1024) { cnt[i] = 0; rank[i] = 0; }
    __syncthreads();
    for (int g = tid; g < NITEMS; g += 1024) {
        int b;
        if (g < NN) {
            b = pos_ids[g];
        } else {
            int j = g - NN + CH_LO;
            int base = CH_LO, sz = 64, l = 2;
            while (j >= base + sz) { base += sz; sz <<= 2; ++l; }
            int c = j - base;
            b = NPOS + (l - 2) * NDEP + dep_ids[base + 1 + c];
        }
        atomicAdd(&cnt[b], 1);
    }
    __syncthreads();
    if (tid == 0) {
        const int gb[6] = {0, 20, 84, 340, 1364, 5460};  // row bases per group
        int b = 0;
        for (int g = 0; g < 6; ++g) {
            int w = (g == 0) ? NPOS : NDEP;
            int off = gb[g], tp = 0;
            for (int i = 0; i < w; ++i, ++b) {
                scb[b] = off; tpre[b] = tp;
                off += cnt[b]; tp += (cnt[b] + 63) >> 6;
            }
            ntiles[g] = tp;
        }
    }
    __syncthreads();
    if (tid < NB) {
        int b = tid;
        int g = (b < NPOS) ? 0 : 1 + (b - NPOS) / NDEP;
        int loc = (b < NPOS) ? b : (b - NPOS) % NDEP;
        int2* tb = (g == 0) ? tbl1 : tblL + (g - 1) * 302;
        int c = cnt[b];
        int t = (c + 63) >> 6;
        for (int k = 0; k < t; ++k) {
            int2 ent;
            ent.x = loc | (min(64, c - (k << 6)) << 8);
            ent.y = scb[b] + (k << 6);
            tb[tpre[b] + k] = ent;
        }
    }
    __syncthreads();
    for (int g = tid; g < NITEMS; g += 1024) {
        int b, payload;
        if (g < NN) {
            b = pos_ids[g]; payload = g;
        } else {
            int j = g - NN + CH_LO;
            int base = CH_LO, sz = 64, l = 2;
            while (j >= base + sz) { base += sz; sz <<= 2; ++l; }
            int c = j - base;
            b = NPOS + (l - 2) * NDEP + dep_ids[base + 1 + c];
            payload = c;
        }
        int r = atomicAdd(&rank[b], 1);
        int idx = scb[b] + r;
        if (b < NPOS) perm_pos[idx] = payload;
        else perm_dep[idx] = payload;
    }
}

// ---- GEMM: 64-row tile x N=128, K=128, 4 waves x (16 rows, 8 n-tiles) ----
// MODE 0: A = bf16(emb[perm[r]]); MODE 1: A = xb[perm[r]];
// MODE 2: A = max(xb[c], uprev[4c+j])
template <int MODE>
__global__ __launch_bounds__(256) void gemm_kernel(
        const int2* __restrict__ tbl, const int* __restrict__ ntp,
        const int* __restrict__ perm, const unsigned short* __restrict__ Wt,
        const float* __restrict__ bias, const float* __restrict__ embf,
        const unsigned short* __restrict__ xb, const unsigned short* __restrict__ uprev,
        unsigned short* __restrict__ outr) {
    int nt = ntp[0];
    if ((int)blockIdx.x >= nt) return;
    int2 e = tbl[blockIdx.x];
    int bucket = e.x & 255;
    int rows = e.x >> 8;
    int rowstart = e.y;
    int lane = threadIdx.x & 63;
    int w = threadIdx.x >> 6;
    int lr = lane & 15;
    int kk = (lane >> 4) * 8;
    const short8 zero8 = {0, 0, 0, 0, 0, 0, 0, 0};

    int m_a = w * 16 + lr;
    bool valid_a = m_a < rows;
    int rid_a = valid_a ? perm[rowstart + m_a] : 0;

    short8 afr[4];
    if (MODE == 0) {
        const float* ar = embf + (size_t)rid_a * DD + kk;
#pragma unroll
        for (int s = 0; s < 4; ++s) {
            float4 lo = *(const float4*)(ar + s * 32);
            float4 hi = *(const float4*)(ar + s * 32 + 4);
            short8 a;
            a[0] = (short)f2bf(lo.x); a[1] = (short)f2bf(lo.y);
            a[2] = (short)f2bf(lo.z); a[3] = (short)f2bf(lo.w);
            a[4] = (short)f2bf(hi.x); a[5] = (short)f2bf(hi.y);
            a[6] = (short)f2bf(hi.z); a[7] = (short)f2bf(hi.w);
            afr[s] = valid_a ? a : zero8;
        }
    } else if (MODE == 1) {
        const unsigned short* ar = xb + (size_t)rid_a * DD + kk;
#pragma unroll
        for (int s = 0; s < 4; ++s)
            afr[s] = valid_a ? *(const short8*)(ar + s * 32) : zero8;
    } else {
        const unsigned short* xr = xb + (size_t)rid_a * DD + kk;
        const unsigned short* ur = uprev + (size_t)(4 * rid_a) * DD + kk;
#pragma unroll
        for (int s = 0; s < 4; ++s) {
            short8 a = *(const short8*)(xr + s * 32);
#pragma unroll
            for (int j = 0; j < 4; ++j) {
                short8 u = *(const short8*)(ur + j * DD + s * 32);
#pragma unroll
                for (int q = 0; q < 8; ++q)
                    if ((unsigned short)u[q] > (unsigned short)a[q]) a[q] = u[q];
            }
            afr[s] = valid_a ? a : zero8;
        }
    }

    f32x4 acc[8];
#pragma unroll
    for (int t = 0; t < 8; ++t) acc[t] = (f32x4){0.f, 0.f, 0.f, 0.f};

    const unsigned short* Wb = Wt + (size_t)bucket * DD * DD;
#pragma unroll
    for (int s = 0; s < 4; ++s) {
        short8 bfr[8];
#pragma unroll
        for (int t = 0; t < 8; ++t)
            bfr[t] = *(const short8*)(Wb + (size_t)(t * 16 + lr) * DD + s * 32 + kk);
#pragma unroll
        for (int t = 0; t < 8; ++t)
            acc[t] = __builtin_amdgcn_mfma_f32_16x16x32_bf16(afr[s], bfr[t], acc[t], 0, 0, 0);
    }

    int rq[4]; bool vq[4];
#pragma unroll
    for (int q = 0; q < 4; ++q) {
        int m = w * 16 + (lane >> 4) * 4 + q;
        vq[q] = m < rows;
        rq[q] = vq[q] ? perm[rowstart + m] : 0;
    }
    const float* bb = bias + bucket * DD;
#pragma unroll
    for (int t = 0; t < 8; ++t) {
        int col = t * 16 + lr;
        float bv = bb[col];
#pragma unroll
        for (int q = 0; q < 4; ++q) {
            if (vq[q]) {
                float v = fmaxf(acc[t][q] + bv, 0.f);
                outr[(size_t)rq[q] * DD + col] = f2bf(v);
            }
        }
    }
}

// ---- D8: parent levels 1, 0 + final. 8 teams x 128 threads, fp32 GEMV. ----
__global__ __launch_bounds__(1024) void tail_kernel(
        const int* __restrict__ dep_ids, const float* __restrict__ depW,
        const float* __restrict__ dep_b, const unsigned short* __restrict__ xbf,
        unsigned short* __restrict__ uarena, float* __restrict__ out) {
    __shared__ float zbuf[8][DD];
    int team = threadIdx.x >> 7, e = threadIdx.x & 127;
    // parent level 1: children c=0..15, did=dep_ids[5+c], z=max(x[5+c],uL2[4c+j])
    {
        const unsigned short* up = uarena + (size_t)21760 * DD;   // uL2 (64 rows)
        unsigned short* uc = uarena + (size_t)21824 * DD;         // uP1 (16 rows)
        for (int rnd = 0; rnd < 2; ++rnd) {
            int c = team + rnd * 8;
            unsigned short m = xbf[(size_t)(5 + c) * DD + e];
#pragma unroll
            for (int j = 0; j < 4; ++j) {
                unsigned short u = up[(size_t)(4 * c + j) * DD + e];
                if (u > m) m = u;
            }
            zbuf[team][e] = bf2f(m);
            __syncthreads();
            int did = dep_ids[5 + c];
            const float* W = depW + (size_t)did * DD * DD;
            float a = dep_b[did * DD + e];
#pragma unroll 8
            for (int k = 0; k < DD; ++k)
                a = fmaf(zbuf[team][k], W[(size_t)k * DD + e], a);
            uc[(size_t)c * DD + e] = f2bf(fmaxf(a, 0.f));
            __syncthreads();
        }
    }
    // parent level 0: children c=0..3 (teams 0..3), did=dep_ids[1+c]
    {
        const unsigned short* up = uarena + (size_t)21824 * DD;   // uP1
        unsigned short* uc = uarena + (size_t)21840 * DD;         // uP0 (4 rows)
        int c = team;
        if (team < 4) {
            unsigned short m = xbf[(size_t)(1 + c) * DD + e];
#pragma unroll
            for (int j = 0; j < 4; ++j) {
                unsigned short u = up[(size_t)(4 * c + j) * DD + e];
                if (u > m) m = u;
            }
            zbuf[team][e] = bf2f(m);
        }
        __syncthreads();
        if (team < 4) {
            int did = dep_ids[1 + c];
            const float* W = depW + (size_t)did * DD * DD;
            float a = dep_b[did * DD + e];
#pragma unroll 8
            for (int k = 0; k < DD; ++k)
                a = fmaf(zbuf[team][k], W[(size_t)k * DD + e], a);
            uc[(size_t)c * DD + e] = f2bf(fmaxf(a, 0.f));
        }
        __syncthreads();
    }
    // final: out = max(x[0], uP0 rows 0..3)
    if (threadIdx.x < DD) {
        unsigned short m = xbf[threadIdx.x];
#pragma unroll
        for (int j = 0; j < 4; ++j) {
            unsigned short u = uarena[(size_t)(21840 + j) * DD + threadIdx.x];
            if (u > m) m = u;
        }
        out[threadIdx.x] = bf2f(m);
    }
}

extern "C" void kernel_launch(void* const* d_in, const int* in_sizes, int n_in,
                              void* d_out, int out_size, void* d_ws, size_t ws_size,
                              hipStream_t stream) {
    const float* emb     = (const float*)d_in[0];
    const int*   pos_ids = (const int*)d_in[1];
    const int*   dep_ids = (const int*)d_in[2];
    const float* pos_W   = (const float*)d_in[3];
    const float* pos_b   = (const float*)d_in[4];
    const float* dep_W   = (const float*)d_in[5];
    const float* dep_b   = (const float*)d_in[6];
    float* out = (float*)d_out;

    char* p = (char*)d_ws;
    auto alloc = [&](size_t bytes) {
        char* r = p; p += (bytes + 255) & ~(size_t)255; return r;
    };
    int*  ntiles   = (int*)alloc(8 * 4);
    int*  perm_pos = (int*)alloc((size_t)NN * 4);
    int*  perm_dep = (int*)alloc((size_t)NCHALL * 4);
    int2* tbl1     = (int2*)alloc(360 * 8);
    int2* tblL     = (int2*)alloc(5 * 302 * 8);
    unsigned short* Wt     = (unsigned short*)alloc((size_t)64 * DD * DD * 2);
    unsigned short* xbf    = (unsigned short*)alloc((size_t)NN * DD * 2);
    unsigned short* uarena = (unsigned short*)alloc((size_t)NCHALL * DD * 2);

    // D1: convert + plan
    prep_kernel<<<257, 1024, 0, stream>>>(pos_W, dep_W, Wt, pos_ids, dep_ids,
                                          perm_pos, perm_dep, ntiles, tbl1, tblL);
    // D2: stage1
    gemm_kernel<0><<<360, 256, 0, stream>>>(tbl1, ntiles + 0, perm_pos, Wt, pos_b,
                                            emb, nullptr, nullptr, xbf);
    const unsigned short* Wtd = Wt + (size_t)NPOS * DD * DD;
    // D3: level 6 (group 5)
    gemm_kernel<1><<<302, 256, 0, stream>>>(tblL + 4 * 302, ntiles + 5, perm_dep,
                                            Wtd, dep_b, nullptr,
                                            xbf + (size_t)5461 * DD, nullptr,
                                            uarena);
    // D4: level 5
    gemm_kernel<2><<<110, 256, 0, stream>>>(tblL + 3 * 302, ntiles + 4, perm_dep,
                                            Wtd, dep_b, nullptr,
                                            xbf + (size_t)1365 * DD, uarena,
                                            uarena + (size_t)16384 * DD);
    // D5: level 4
    gemm_kernel<2><<<62, 256, 0, stream>>>(tblL + 2 * 302, ntiles + 3, perm_dep,
                                           Wtd, dep_b, nullptr,
                                           xbf + (size_t)341 * DD,
                                           uarena + (size_t)16384 * DD,
                                           uarena + (size_t)20480 * DD);
    // D6: level 3
    gemm_kernel<2><<<50, 256, 0, stream>>>(tblL + 1 * 302, ntiles + 2, perm_dep,
                                           Wtd, dep_b, nullptr,
                                           xbf + (size_t)85 * DD,
                                           uarena + (size_t)20480 * DD,
                                           uarena + (size_t)21504 * DD);
    // D7: level 2
    gemm_kernel<2><<<46, 256, 0, stream>>>(tblL + 0 * 302, ntiles + 1, perm_dep,
                                           Wtd, dep_b, nullptr,
                                           xbf + (size_t)21 * DD,
                                           uarena + (size_t)21504 * DD,
                                           uarena + (size_t)21760 * DD);
    // D8: levels 1,0 + final
    tail_kernel<<<1, 1024, 0, stream>>>(dep_ids, dep_W, dep_b, xbf, uarena, out);
}